// Round 6
// baseline (523.505 us; speedup 1.0000x reference)
//
#include <hip/hip_runtime.h>
#include <stdint.h>

#define S_LEN 256
#define DIM   128
#define EPSL  1e-5f

typedef __bf16 bf16x8 __attribute__((ext_vector_type(8)));
typedef float  f32x4  __attribute__((ext_vector_type(4)));

__device__ __forceinline__ unsigned short f2bf_bits(float f) {
  union { float f; unsigned int u; } v; v.f = f;
  unsigned int r = v.u + 0x7fffu + ((v.u >> 16) & 1u);   // RTNE (init paths)
  return (unsigned short)(r >> 16);
}
__device__ __forceinline__ unsigned f2bf_rhu(float f) {
  return (__float_as_uint(f) + 0x8000u) >> 16;
}
__device__ __forceinline__ unsigned pack_rhu(float lo, float hi) {
  return __builtin_amdgcn_perm(__float_as_uint(hi) + 0x8000u,
                               __float_as_uint(lo) + 0x8000u, 0x07060302u);
}
// tanh(x) = 1 - 2/(e^{2x}+1): ~1e-6 rel err, exact at +-inf.
__device__ __forceinline__ float tanh_fast(float x) {
  float e = __expf(2.f * x);
  return 1.f - 2.f * __builtin_amdgcn_rcpf(e + 1.f);
}

template<int CTRL>
__device__ __forceinline__ float dpp_rot_add(float v) {
  int r = __builtin_amdgcn_update_dpp(0, __float_as_int(v), CTRL, 0xF, 0xF, true);
  return v + __int_as_float(r);
}
template<int CTRL>
__device__ __forceinline__ float dpp_rot_max(float v) {
  int r = __builtin_amdgcn_update_dpp(0, __float_as_int(v), CTRL, 0xF, 0xF, true);
  return fmaxf(v, __int_as_float(r));
}
__device__ __forceinline__ float dpp_sum16(float v) {
  v = dpp_rot_add<0x124>(v); v = dpp_rot_add<0x128>(v);
  v = dpp_rot_add<0x39>(v);  v = dpp_rot_add<0x4E>(v);
  return v;
}
__device__ __forceinline__ float dpp_max16(float v) {
  v = dpp_rot_max<0x124>(v); v = dpp_rot_max<0x128>(v);
  v = dpp_rot_max<0x39>(v);  v = dpp_rot_max<0x4E>(v);
  return v;
}
template<int CTRL>
__device__ __forceinline__ void red_level7(float& s, float& sq, float* d) {
  s  = dpp_rot_add<CTRL>(s);
  sq = dpp_rot_add<CTRL>(sq);
#pragma unroll
  for (int j = 0; j < 5; j++) d[j] = dpp_rot_add<CTRL>(d[j]);
}
template<int JJ>
__device__ __forceinline__ float bcast16(float v) {
  int r = __builtin_amdgcn_ds_swizzle(__float_as_int(v), (JJ << 5) | 0x10);
  return __int_as_float(r);
}

union Frag8 { unsigned short us[8]; bf16x8 v; int4 i4; };

// ============ rnn_wavecore: WAVE-PRIVATE recurrence, zero barriers ==========
// Core blocks (0..127): ONE working wave (waves 1-3 exit), 8 batch rows each.
// The wave owns the full 128-dim recurrence for its rows: rows sit in MFMA
// M-slots {q*4+r, r in {0,1}} (all 64 lanes hold real tanh values). Per step:
// 4 private ds_read_b128 (h A-frags), 8 N-tile x depth-4 MFMA chains
// (summation order identical to the verified R5 kernel -> bit-identical
// output), 16 tanh, 16 ds_write_u16 into a wave-private 4KB h tile. No
// s_barrier in the serial loop: in-wave LDS ordering is sufficient. xp
// production (32 MFMAs), e-gather (2-step latency cover), hout stores (via
// the A-frags just read = h_{t-1}), and chunk-flag publishes ride off-chain
// in the same wave. Whh+Wih held in registers (~256 VGPR of weights).
// Tail blocks (128..255): R4's verified 8-row/4-wave tail, paired 1:1.
__global__ __launch_bounds__(256, 1)
void rnn_wavecore(const int* __restrict__ x, const float* __restrict__ emb,
                  const float* __restrict__ Wih1, const float* __restrict__ bih1,
                  const float* __restrict__ Whh1, const float* __restrict__ bhh1,
                  const float* __restrict__ g1, const float* __restrict__ be1,
                  const float* __restrict__ Wih2, const float* __restrict__ bih2,
                  const float* __restrict__ Whh2, const float* __restrict__ bhh2,
                  const float* __restrict__ g2, const float* __restrict__ be2,
                  unsigned short* __restrict__ hout, int* flags,
                  float* __restrict__ out)
{
  __shared__ __align__(16) unsigned short h_priv[16 * 128];   // 4 KB (core)
  __shared__ __align__(16) float p_lds[4][2][32][8];          // 8 KB (tail)

  const int tid  = threadIdx.x;
  const int lane = tid & 63;
  const int l15  = lane & 15;
  const int q    = lane >> 4;

  if (blockIdx.x < 128) {
    // ========================= CORE ROLE (wave 0 only) =========================
    if (tid >= 64) return;
    const int r0   = blockIdx.x * 8;
    const bool arow = ((l15 & 2) == 0);               // l15 is a live M-slot
    const int rowi  = ((l15 >> 2) << 1) | (l15 & 1);  // slot -> row 0..7
    const size_t growu = (size_t)(r0 + rowi);

    // zero private h (rows never written stay 0 -> clean A garbage rows)
    {
      int4 z = {0, 0, 0, 0};
#pragma unroll
      for (int i = 0; i < 4; i++)
        *(int4*)&h_priv[(i * 64 + lane) * 8] = z;
    }

    // weights + bias, all in registers
    float biasx[8];
    bf16x8 whh[8][4], wih[8][4];
#pragma unroll
    for (int tile = 0; tile < 8; tile++) {
      const int d = tile * 16 + l15;
      biasx[tile] = bih1[d] + bhh1[d];
#pragma unroll
      for (int kt = 0; kt < 4; kt++) {
        Frag8 fh, fa;
#pragma unroll
        for (int j = 0; j < 8; j++) {
          fh.us[j] = f2bf_bits(Whh1[d * DIM + kt * 32 + q * 8 + j]);
          fa.us[j] = f2bf_bits(Wih1[d * DIM + kt * 32 + q * 8 + j]);
        }
        whh[tile][kt] = fh.v; wih[tile][kt] = fa.v;
      }
    }

    int ra[4];                                        // A-frag read addrs
#pragma unroll
    for (int kt = 0; kt < 4; kt++)
      ra[kt] = l15 * 128 + (((kt * 4 + q) ^ l15) & 15) * 8;

    auto eload = [&](float4* eld, int xid) {          // gather e row (f32)
      const float* pe = emb + (size_t)xid * DIM + q * 8;
#pragma unroll
      for (int kt = 0; kt < 4; kt++) {
        eld[kt * 2]     = *(const float4*)(pe + kt * 32);
        eld[kt * 2 + 1] = *(const float4*)(pe + kt * 32 + 4);
      }
    };
    auto epack = [&](Frag8* frag, const float4* eld) {
#pragma unroll
      for (int kt = 0; kt < 4; kt++) {
        frag[kt].i4.x = (int)pack_rhu(eld[kt * 2].x,     eld[kt * 2].y);
        frag[kt].i4.y = (int)pack_rhu(eld[kt * 2].z,     eld[kt * 2].w);
        frag[kt].i4.z = (int)pack_rhu(eld[kt * 2 + 1].x, eld[kt * 2 + 1].y);
        frag[kt].i4.w = (int)pack_rhu(eld[kt * 2 + 1].z, eld[kt * 2 + 1].w);
      }
    };
    auto produce = [&](f32x4* xp, const Frag8* frag) { // xp = bias + e@Wih^T
#pragma unroll
      for (int tile = 0; tile < 8; tile++) {
        f32x4 a = {biasx[tile], biasx[tile], biasx[tile], biasx[tile]};
#pragma unroll
        for (int kt = 0; kt < 4; kt++)
          a = __builtin_amdgcn_mfma_f32_16x16x32_bf16(frag[kt].v, wih[tile][kt], a, 0, 0, 0);
        xp[tile] = a;
      }
    };
    auto sstep = [&](int t, const f32x4* xp) {
      bf16x8 ha[4];                                   // h_{t-1} A-frags
#pragma unroll
      for (int kt = 0; kt < 4; kt++)
        ha[kt] = *(const bf16x8*)&h_priv[ra[kt]];
      if (t > 0 && arow) {                            // hout <- h_{t-1}
        unsigned short* hp = hout + (growu * S_LEN + (t - 1)) * DIM + q * 8;
#pragma unroll
        for (int kt = 0; kt < 4; kt++)
          *(int4*)(hp + kt * 32) = *(const int4*)&ha[kt];
      }
#pragma unroll
      for (int tile = 0; tile < 8; tile++) {          // depth-4 chain (R5 order)
        f32x4 acc = xp[tile];
#pragma unroll
        for (int kt = 0; kt < 4; kt++)
          acc = __builtin_amdgcn_mfma_f32_16x16x32_bf16(ha[kt], whh[tile][kt], acc, 0, 0, 0);
        const int oct = tile * 2 + (l15 >> 3);
#pragma unroll
        for (int r = 0; r < 2; r++) {                 // live slots only
          const int m = q * 4 + r;
          h_priv[m * 128 + ((oct ^ m) & 15) * 8 + (l15 & 7)] =
              (unsigned short)f2bf_rhu(tanh_fast(acc[r]));
        }
      }
    };

    // ---- prologue: frag=e1, eldA=e2, eldB=e3, xidA=x4, xidB=x5, xpA=xp0 ----
    float4 eldA[8], eldB[8];
    Frag8  frag[4];
    f32x4  xpA[8], xpB[8];
    int xidA, xidB;
    {
      int xid0 = x[growu * S_LEN + 0];
      eload(eldA, xid0); epack(frag, eldA); produce(xpA, frag);
      int xid1 = x[growu * S_LEN + 1];
      eload(eldA, xid1); epack(frag, eldA);
      int xid2 = x[growu * S_LEN + 2];
      eload(eldA, xid2);
      int xid3 = x[growu * S_LEN + 3];
      eload(eldB, xid3);
      xidA = x[growu * S_LEN + 4];
      xidB = x[growu * S_LEN + 5];
    }

    for (int tp = 0; tp < S_LEN / 2; tp++) {
      const int t0 = 2 * tp, t1 = t0 + 1;
      // -------- even step --------
      sstep(t0, xpA);
      if (flags != nullptr && t0 > 0 && (t0 & 31) == 0) {
        asm volatile("s_waitcnt vmcnt(0)" ::: "memory");   // drain hout
        if (lane == 0)
          __hip_atomic_store(&flags[blockIdx.x * 8 + (t0 >> 5) - 1], t0 >> 5,
                             __ATOMIC_RELEASE, __HIP_MEMORY_SCOPE_AGENT);
      }
      if (t0 + 1 < S_LEN) produce(xpB, frag);
      if (t0 + 2 < S_LEN) epack(frag, eldA);
      if (t0 + 4 < S_LEN) eload(eldA, xidA);
      if (t0 + 6 < S_LEN) xidA = x[growu * S_LEN + t0 + 6];
      // -------- odd step --------
      sstep(t1, xpB);
      if (t1 + 1 < S_LEN) produce(xpA, frag);
      if (t1 + 2 < S_LEN) epack(frag, eldB);
      if (t1 + 4 < S_LEN) eload(eldB, xidB);
      if (t1 + 6 < S_LEN) xidB = x[growu * S_LEN + t1 + 6];
    }
    // ---- epilogue: store h_{255}, publish final chunk ----
    {
      bf16x8 ha[4];
#pragma unroll
      for (int kt = 0; kt < 4; kt++)
        ha[kt] = *(const bf16x8*)&h_priv[ra[kt]];
      if (arow) {
        unsigned short* hp = hout + (growu * S_LEN + (S_LEN - 1)) * DIM + q * 8;
#pragma unroll
        for (int kt = 0; kt < 4; kt++)
          *(int4*)(hp + kt * 32) = *(const int4*)&ha[kt];
      }
      if (flags != nullptr) {
        asm volatile("s_waitcnt vmcnt(0)" ::: "memory");
        if (lane == 0)
          __hip_atomic_store(&flags[blockIdx.x * 8 + 7], 8,
                             __ATOMIC_RELEASE, __HIP_MEMORY_SCOPE_AGENT);
      }
    }
  } else {
    // ========================= TAIL ROLE (R4-verified) =========================
    const int bt = blockIdx.x - 128;     // 0..127, rows bt*8 .. bt*8+7
    const int wave = tid >> 6;
    float w2g[5][8], Gs[5], Bs[5], wrow[5];
#pragma unroll
    for (int j = 0; j < 8; j++) {
      int c = l15 * 8 + j;               // plain row-major channels
      float gc = g1[c];
#pragma unroll
      for (int jj = 0; jj < 5; jj++) w2g[jj][j] = Wih2[jj * DIM + c] * gc;
    }
#pragma unroll
    for (int jj = 0; jj < 5; jj++) { Gs[jj] = 0.f; Bs[jj] = 0.f; }
    for (int c = 0; c < DIM; c++) {
      float gc = g1[c], bc = be1[c];
#pragma unroll
      for (int jj = 0; jj < 5; jj++) {
        float w = Wih2[jj * DIM + c];
        Gs[jj] += w * gc; Bs[jj] += w * bc;
      }
    }
    const float validf = (l15 < 5) ? 1.f : 0.f;
    float t2_l = 0.f, g2_l = 0.f, be2_l = 0.f;
    if (l15 < 5) {
      t2_l = bih2[l15] + bhh2[l15];
      g2_l = g2[l15]; be2_l = be2[l15];
#pragma unroll
      for (int jj = 0; jj < 5; jj++) wrow[jj] = Whh2[l15 * 5 + jj];
    } else {
#pragma unroll
      for (int jj = 0; jj < 5; jj++) wrow[jj] = 0.f;
    }
    float h2rep[5] = {0, 0, 0, 0, 0}, pool_l = 0.f;
    const int rowg = bt * 8 + wave * 2 + (q & 1);   // this group's row
    const unsigned short* hb = hout + (size_t)rowg * S_LEN * DIM;
    const int idx = (l15 < 5) ? l15 : 0;

    for (int c8 = 0; c8 < 8; c8++) {
      if (tid == 0) {                    // poisoned flag is negative: waits
        while (__hip_atomic_load(&flags[bt * 8 + c8], __ATOMIC_RELAXED,
                                 __HIP_MEMORY_SCOPE_AGENT) < c8 + 1)
          __builtin_amdgcn_s_sleep(2);
      }
      __syncthreads();
      __builtin_amdgcn_fence(__ATOMIC_ACQUIRE, "agent");   // reader-side inv
      // phase A: LN1+proj for this chunk (2 rows x 32 t over 2 sub-groups)
      for (int tt = 0; tt < 16; tt++) {
        int toff = tt * 2 + (q >> 1);
        uint4 cur = *(const uint4*)(hb + (size_t)(c8 * 32 + toff) * DIM + l15 * 8);
        float hv[8];
        hv[0] = __uint_as_float(cur.x << 16); hv[1] = __uint_as_float(cur.x & 0xffff0000u);
        hv[2] = __uint_as_float(cur.y << 16); hv[3] = __uint_as_float(cur.y & 0xffff0000u);
        hv[4] = __uint_as_float(cur.z << 16); hv[5] = __uint_as_float(cur.z & 0xffff0000u);
        hv[6] = __uint_as_float(cur.w << 16); hv[7] = __uint_as_float(cur.w & 0xffff0000u);
        float s = 0.f, sq = 0.f, d[5] = {0, 0, 0, 0, 0};
#pragma unroll
        for (int j = 0; j < 8; j++) {
          float v = hv[j];
          s += v; sq += v * v;
#pragma unroll
          for (int jj = 0; jj < 5; jj++) d[jj] = fmaf(w2g[jj][j], v, d[jj]);
        }
        red_level7<0x124>(s, sq, d);
        red_level7<0x128>(s, sq, d);
        red_level7<0x39>(s, sq, d);
        red_level7<0x4E>(s, sq, d);
        float mean = s * (1.f / 128.f);
        float var  = sq * (1.f / 128.f) - mean * mean;
        float rstd = rsqrtf(var + EPSL);
        float p[5];
#pragma unroll
        for (int jj = 0; jj < 5; jj++)
          p[jj] = rstd * (d[jj] - mean * Gs[jj]) + Bs[jj];
        float psel = (l15 == 0) ? p[0] : (l15 == 1) ? p[1] :
                     (l15 == 2) ? p[2] : (l15 == 3) ? p[3] : p[4];
        if (l15 < 5) p_lds[wave][q & 1][toff][l15] = psel;
      }
      asm volatile("s_waitcnt lgkmcnt(0)" ::: "memory");   // wave-local
      // phase B: 32 serial RNN2/LN2/pool steps (group-local, 1 tanh/step)
      for (int s = 0; s < 32; s++) {
        float pv = p_lds[wave][q & 1][s][idx];
        float a = pv + t2_l;
#pragma unroll
        for (int jj = 0; jj < 5; jj++) a = fmaf(wrow[jj], h2rep[jj], a);
        float xn = tanh_fast(a);
        float s2 = dpp_sum16(xn * validf) * 0.2f;
        float dd = xn - s2;
        float v2 = dpp_sum16(dd * dd * validf) * 0.2f;
        float r2 = rsqrtf(v2 + EPSL);
        pool_l += dd * r2 * g2_l + be2_l;
        h2rep[0] = bcast16<0>(xn); h2rep[1] = bcast16<1>(xn);
        h2rep[2] = bcast16<2>(xn); h2rep[3] = bcast16<3>(xn);
        h2rep[4] = bcast16<4>(xn);
      }
    }
    float lg = pool_l * (1.f / 256.f);
    float mx = dpp_max16((l15 < 5) ? lg : -3.0e38f);
    float e  = (l15 < 5) ? __expf(lg - mx) : 0.f;
    float sm = dpp_sum16(e);
    if (q < 2 && l15 < 5)
      out[(size_t)rowg * 5 + l15] = e / sm;
  }
}

// ============ rnn_tail_r11: fallback tail (ws too small for flags) =========
__global__ __launch_bounds__(256, 2)
void rnn_tail_r11(const unsigned short* __restrict__ hall,
                  const float* __restrict__ g1,  const float* __restrict__ be1,
                  const float* __restrict__ Wih2, const float* __restrict__ bih2,
                  const float* __restrict__ Whh2, const float* __restrict__ bhh2,
                  const float* __restrict__ g2,  const float* __restrict__ be2,
                  float* __restrict__ out)
{
  __shared__ float p_lds[4][4][8];
  const int tid  = threadIdx.x;
  const int wave = tid >> 6;
  const int lane = tid & 63;
  const int l15  = lane & 15;
  const int q    = lane >> 4;
  const int b    = blockIdx.x * 4 + wave;

  float w2g[5][8], Gs[5], Bs[5], wrow[5];
#pragma unroll
  for (int j = 0; j < 8; j++) {
    int c = l15 * 8 + j;
    float gc = g1[c];
#pragma unroll
    for (int jj = 0; jj < 5; jj++) w2g[jj][j] = Wih2[jj * DIM + c] * gc;
  }
#pragma unroll
  for (int jj = 0; jj < 5; jj++) { Gs[jj] = 0.f; Bs[jj] = 0.f; }
  for (int c = 0; c < DIM; c++) {
    float gc = g1[c], bc = be1[c];
#pragma unroll
    for (int jj = 0; jj < 5; jj++) {
      float w = Wih2[jj * DIM + c];
      Gs[jj] += w * gc; Bs[jj] += w * bc;
    }
  }
  const float validf = (l15 < 5) ? 1.f : 0.f;
  float t2_l = 0.f, g2_l = 0.f, be2_l = 0.f;
  if (l15 < 5) {
    t2_l = bih2[l15] + bhh2[l15];
    g2_l = g2[l15]; be2_l = be2[l15];
#pragma unroll
    for (int jj = 0; jj < 5; jj++) wrow[jj] = Whh2[l15 * 5 + jj];
  } else {
#pragma unroll
    for (int jj = 0; jj < 5; jj++) wrow[jj] = 0.f;
  }
  float h2rep[5];
#pragma unroll
  for (int jj = 0; jj < 5; jj++) h2rep[jj] = 0.f;
  float pool_l = 0.f;

  const unsigned short* hb = hall + (size_t)b * S_LEN * DIM;
  uint4 hpre = *(const uint4*)(hb + (size_t)q * DIM + l15 * 8);

  for (int t0 = 0; t0 < S_LEN; t0 += 4) {
    uint4 cur = hpre;
    if (t0 + 4 < S_LEN)
      hpre = *(const uint4*)(hb + (size_t)(t0 + 4 + q) * DIM + l15 * 8);
    float hv[8];
    hv[0] = __uint_as_float(cur.x << 16); hv[1] = __uint_as_float(cur.x & 0xffff0000u);
    hv[2] = __uint_as_float(cur.y << 16); hv[3] = __uint_as_float(cur.y & 0xffff0000u);
    hv[4] = __uint_as_float(cur.z << 16); hv[5] = __uint_as_float(cur.z & 0xffff0000u);
    hv[6] = __uint_as_float(cur.w << 16); hv[7] = __uint_as_float(cur.w & 0xffff0000u);
    float s = 0.f, sq = 0.f, d[5] = {0, 0, 0, 0, 0};
#pragma unroll
    for (int j = 0; j < 8; j++) {
      float v = hv[j];
      s += v; sq += v * v;
#pragma unroll
      for (int jj = 0; jj < 5; jj++) d[jj] = fmaf(w2g[jj][j], v, d[jj]);
    }
    red_level7<0x124>(s, sq, d);
    red_level7<0x128>(s, sq, d);
    red_level7<0x39>(s, sq, d);
    red_level7<0x4E>(s, sq, d);
    float mean = s * (1.f / 128.f);
    float var  = sq * (1.f / 128.f) - mean * mean;
    float rstd = rsqrtf(var + EPSL);
    float p[5];
#pragma unroll
    for (int jj = 0; jj < 5; jj++)
      p[jj] = rstd * (d[jj] - mean * Gs[jj]) + Bs[jj];
    float psel = (l15 == 0) ? p[0] : (l15 == 1) ? p[1] :
                 (l15 == 2) ? p[2] : (l15 == 3) ? p[3] : p[4];
    if (l15 < 5) p_lds[wave][q][l15] = psel;
    asm volatile("s_waitcnt lgkmcnt(0)" ::: "memory");
    const int idx = (l15 < 5) ? l15 : 0;
#pragma unroll
    for (int g = 0; g < 4; g++) {
      float pv = p_lds[wave][g][idx];
      float a = pv + t2_l;
#pragma unroll
      for (int jj = 0; jj < 5; jj++) a = fmaf(wrow[jj], h2rep[jj], a);
      float xn = tanh_fast(a);
      float s2 = dpp_sum16(xn * validf) * 0.2f;
      float dd = xn - s2;
      float v2 = dpp_sum16(dd * dd * validf) * 0.2f;
      float r2 = rsqrtf(v2 + EPSL);
      pool_l += dd * r2 * g2_l + be2_l;
      h2rep[0] = bcast16<0>(xn); h2rep[1] = bcast16<1>(xn);
      h2rep[2] = bcast16<2>(xn); h2rep[3] = bcast16<3>(xn);
      h2rep[4] = bcast16<4>(xn);
    }
  }

  float lg = pool_l * (1.f / 256.f);
  float mx = dpp_max16((l15 < 5) ? lg : -3.0e38f);
  float e  = (l15 < 5) ? __expf(lg - mx) : 0.f;
  float sm = dpp_sum16(e);
  if (q == 0 && l15 < 5) out[(size_t)b * 5 + l15] = e / sm;
}

extern "C" void kernel_launch(void* const* d_in, const int* in_sizes, int n_in,
                              void* d_out, int out_size, void* d_ws, size_t ws_size,
                              hipStream_t stream) {
  (void)in_sizes; (void)n_in; (void)out_size;
  const int*   x    = (const int*)  d_in[0];
  const float* emb  = (const float*)d_in[1];
  const float* Wih1 = (const float*)d_in[2];
  const float* bih1 = (const float*)d_in[3];
  const float* Whh1 = (const float*)d_in[4];
  const float* bhh1 = (const float*)d_in[5];
  const float* g1   = (const float*)d_in[6];
  const float* be1  = (const float*)d_in[7];
  const float* Wih2 = (const float*)d_in[8];
  const float* bih2 = (const float*)d_in[9];
  const float* Whh2 = (const float*)d_in[10];
  const float* bhh2 = (const float*)d_in[11];
  const float* g2   = (const float*)d_in[12];
  const float* be2  = (const float*)d_in[13];
  float* out = (float*)d_out;

  const size_t HBYTES = (size_t)1024 * S_LEN * DIM * 2;   // 64 MiB bf16 h
  unsigned short* hws = (unsigned short*)d_ws;

  if (ws_size >= HBYTES + 4096) {                          // 128*8*4 = 4096
    int* flags = (int*)((char*)d_ws + HBYTES);
    rnn_wavecore<<<dim3(256), dim3(256), 0, stream>>>(
        x, emb, Wih1, bih1, Whh1, bhh1, g1, be1,
        Wih2, bih2, Whh2, bhh2, g2, be2, hws, flags, out);
  } else {
    // fallback: core-only (blocks 0..127, flags = nullptr) + R11 tail
    rnn_wavecore<<<dim3(128), dim3(256), 0, stream>>>(
        x, emb, Wih1, bih1, Whh1, bhh1, g1, be1,
        Wih2, bih2, Whh2, bhh2, g2, be2, hws, nullptr, out);
    rnn_tail_r11<<<dim3(256), dim3(256), 0, stream>>>(
        hws, g1, be1, Wih2, bih2, Whh2, bhh2, g2, be2, out);
  }
}

// Round 7
// 355.194 us; speedup vs baseline: 1.4739x; 1.4739x over previous
//
#include <hip/hip_runtime.h>
#include <stdint.h>

#define S_LEN 256
#define DIM   128
#define EPSL  1e-5f

typedef __bf16 bf16x8 __attribute__((ext_vector_type(8)));
typedef float  f32x4  __attribute__((ext_vector_type(4)));

__device__ __forceinline__ unsigned short f2bf_bits(float f) {
  union { float f; unsigned int u; } v; v.f = f;
  unsigned int r = v.u + 0x7fffu + ((v.u >> 16) & 1u);   // RTNE (init paths)
  return (unsigned short)(r >> 16);
}
__device__ __forceinline__ unsigned f2bf_rhu(float f) {
  return (__float_as_uint(f) + 0x8000u) >> 16;
}
__device__ __forceinline__ unsigned pack_rhu(float lo, float hi) {
  return __builtin_amdgcn_perm(__float_as_uint(hi) + 0x8000u,
                               __float_as_uint(lo) + 0x8000u, 0x07060302u);
}
// tanh(x) = 1 - 2/(e^{2x}+1): ~1e-6 rel err, exact at +-inf.
__device__ __forceinline__ float tanh_fast(float x) {
  float e = __expf(2.f * x);
  return 1.f - 2.f * __builtin_amdgcn_rcpf(e + 1.f);
}

template<int CTRL>
__device__ __forceinline__ float dpp_rot_add(float v) {
  int r = __builtin_amdgcn_update_dpp(0, __float_as_int(v), CTRL, 0xF, 0xF, true);
  return v + __int_as_float(r);
}
template<int CTRL>
__device__ __forceinline__ float dpp_rot_max(float v) {
  int r = __builtin_amdgcn_update_dpp(0, __float_as_int(v), CTRL, 0xF, 0xF, true);
  return fmaxf(v, __int_as_float(r));
}
__device__ __forceinline__ float dpp_sum16(float v) {
  v = dpp_rot_add<0x124>(v); v = dpp_rot_add<0x128>(v);
  v = dpp_rot_add<0x39>(v);  v = dpp_rot_add<0x4E>(v);
  return v;
}
__device__ __forceinline__ float dpp_max16(float v) {
  v = dpp_rot_max<0x124>(v); v = dpp_rot_max<0x128>(v);
  v = dpp_rot_max<0x39>(v);  v = dpp_rot_max<0x4E>(v);
  return v;
}
template<int CTRL>
__device__ __forceinline__ void red_level7(float& s, float& sq, float* d) {
  s  = dpp_rot_add<CTRL>(s);
  sq = dpp_rot_add<CTRL>(sq);
#pragma unroll
  for (int j = 0; j < 5; j++) d[j] = dpp_rot_add<CTRL>(d[j]);
}
template<int JJ>
__device__ __forceinline__ float bcast16(float v) {
  int r = __builtin_amdgcn_ds_swizzle(__float_as_int(v), (JJ << 5) | 0x10);
  return __int_as_float(r);
}

union Frag8 { unsigned short us[8]; bf16x8 v; int4 i4; };

// ================= rnn_xp: xproj hoisted out of the serial phase ============
// Core blocks (0-63), 8 waves (2/SIMD — measured optimum). PHASE 1: each wave
// computes xp = bias + e@Wih for 32 of the block's 256 steps (e gathered
// straight from emb, pack_rhu, 8 N-tiles x depth-4 MFMA seeded with bias —
// identical arithmetic order to the verified R5 kernel -> bit-identical xp),
// stored f32 to a per-block 2MB global buffer. PHASE 2 (serial): per wave per
// step only the true chain remains: in-register xp seed (global f32x4
// prefetched 2 steps ahead, off-chain), 4 ds_read_b128 (h A-frags), depth-4
// MFMA chain, 4x tanh + h_bf write + hout store, one barrier. Per-wave
// stream ~28 instrs (was ~55), per-wave LDS traffic 4.5KB/step (was 8.5KB).
// Tail blocks (64-127) and the chunk-flag protocol are identical to R5.
__global__ __launch_bounds__(512, 2)
void rnn_xp(const int* __restrict__ x, const float* __restrict__ emb,
            const float* __restrict__ Wih1, const float* __restrict__ bih1,
            const float* __restrict__ Whh1, const float* __restrict__ bhh1,
            const float* __restrict__ g1, const float* __restrict__ be1,
            const float* __restrict__ Wih2, const float* __restrict__ bih2,
            const float* __restrict__ Whh2, const float* __restrict__ bhh2,
            const float* __restrict__ g2, const float* __restrict__ be2,
            unsigned short* __restrict__ hout, int* flags,
            float* __restrict__ xpg, float* __restrict__ out)
{
  __shared__ __align__(16) unsigned short h_bf[2][16 * 128];   // 8 KB
  __shared__ int x_tile[16 * 256];                             // 16 KB
  __shared__ __align__(16) float p_lds[8][2][32][8];           // 16 KB (tail)

  const int tid  = threadIdx.x;
  const int wave = tid >> 6;
  const int lane = tid & 63;
  const int l15  = lane & 15;
  const int q    = lane >> 4;

  if (blockIdx.x < 64) {
    // ========================= CORE ROLE =========================
    const int r0 = blockIdx.x * 16;
    float* xpb = xpg + (size_t)blockIdx.x * (S_LEN * 8 * 64 * 4);

    for (int i = tid; i < 16 * 256; i += 512)
      x_tile[i] = x[(size_t)(r0 + (i >> 8)) * S_LEN + (i & 255)];
    __syncthreads();

    // ---------------- PHASE 1: xp burst (this wave: steps t0w..t0w+31) -----
    {
      float biasx[8];
      bf16x8 wihA[8][4];
#pragma unroll
      for (int tile = 0; tile < 8; tile++) {
        const int d = tile * 16 + l15;
        biasx[tile] = bih1[d] + bhh1[d];
#pragma unroll
        for (int kt = 0; kt < 4; kt++) {
          Frag8 fa;
#pragma unroll
          for (int j = 0; j < 8; j++)
            fa.us[j] = f2bf_bits(Wih1[d * DIM + kt * 32 + q * 8 + j]);
          wihA[tile][kt] = fa.v;
        }
      }
      const int t0w = wave * 32;
      float4 eldA[8], eldB[8];
      auto eload = [&](float4* e, int t) {
        int xid = x_tile[l15 * 256 + t];
        const float* pe = emb + (size_t)xid * DIM + q * 8;
#pragma unroll
        for (int kt = 0; kt < 4; kt++) {
          e[kt * 2]     = *(const float4*)(pe + kt * 32);
          e[kt * 2 + 1] = *(const float4*)(pe + kt * 32 + 4);
        }
      };
      auto p1step = [&](int s, float4* ecur) {
        Frag8 fr[4];
#pragma unroll
        for (int kt = 0; kt < 4; kt++) {
          fr[kt].i4.x = (int)pack_rhu(ecur[kt * 2].x,     ecur[kt * 2].y);
          fr[kt].i4.y = (int)pack_rhu(ecur[kt * 2].z,     ecur[kt * 2].w);
          fr[kt].i4.z = (int)pack_rhu(ecur[kt * 2 + 1].x, ecur[kt * 2 + 1].y);
          fr[kt].i4.w = (int)pack_rhu(ecur[kt * 2 + 1].z, ecur[kt * 2 + 1].w);
        }
        if (s + 2 < 32) eload(ecur, t0w + s + 2);   // prefetch into same buf
#pragma unroll
        for (int tile = 0; tile < 8; tile++) {      // depth-4 chain, R5 order
          f32x4 a = {biasx[tile], biasx[tile], biasx[tile], biasx[tile]};
#pragma unroll
          for (int kt = 0; kt < 4; kt++)
            a = __builtin_amdgcn_mfma_f32_16x16x32_bf16(fr[kt].v, wihA[tile][kt], a, 0, 0, 0);
          *(f32x4*)(xpb + (((size_t)(t0w + s) * 8 + tile) * 64 + lane) * 4) = a;
        }
      };
      eload(eldA, t0w); eload(eldB, t0w + 1);
      for (int s = 0; s < 32; s += 2) {
        p1step(s, eldA);
        p1step(s + 1, eldB);
      }
    }
    asm volatile("s_waitcnt vmcnt(0)" ::: "memory");  // xp stores drained
    __syncthreads();                                  // all waves' xp visible

    // ---------------- PHASE 2: minimal serial recurrence -------------------
    for (int i = tid; i < 16 * 128; i += 512) h_bf[1][i] = 0;  // h_{-1} = 0
    const int n1 = wave * 16 + l15;
    bf16x8 wh[4];
#pragma unroll
    for (int kt = 0; kt < 4; kt++) {
      Frag8 fh;
#pragma unroll
      for (int j = 0; j < 8; j++)
        fh.us[j] = f2bf_bits(Whh1[n1 * DIM + kt * 32 + q * 8 + j]);
      wh[kt] = fh.v;
    }
    const float* xpw = xpb + ((size_t)wave * 64 + lane) * 4;  // own N-tile
    f32x4 xprA = *(const f32x4*)(xpw + (size_t)0 * 2048);
    f32x4 xprB = *(const f32x4*)(xpw + (size_t)1 * 2048);
    asm volatile("s_waitcnt lgkmcnt(0)\n\ts_barrier" ::: "memory");

    auto sstep = [&](int t, const f32x4 xpcur) {
      f32x4 acc = xpcur;
      const int rb = (t + 1) & 1;        // h_{t-1}
#pragma unroll
      for (int kt = 0; kt < 4; kt++) {
        int sw = (((kt * 4 + q) ^ l15) & 15) * 8;
        bf16x8 ahf = *(const bf16x8*)&h_bf[rb][l15 * 128 + sw];
        acc = __builtin_amdgcn_mfma_f32_16x16x32_bf16(ahf, wh[kt], acc, 0, 0, 0);
      }
      const int wb = t & 1;
      const int oct = n1 >> 3;
#pragma unroll
      for (int r = 0; r < 4; r++) {      // D-layout: row = q*4 + r, col = l15
        int row = q * 4 + r;
        unsigned short us = (unsigned short)f2bf_rhu(tanh_fast(acc[r]));
        h_bf[wb][row * 128 + ((oct ^ row) & 15) * 8 + (n1 & 7)] = us;
        hout[((size_t)(r0 + row) * S_LEN + t) * DIM + n1] = us;  // off-chain
      }
      // chunk boundary: drain h stores so the post-barrier flag publish
      // covers the whole block's chunk.
      if (flags != nullptr && (t & 31) == 31)
        asm volatile("s_waitcnt vmcnt(0)" ::: "memory");
      asm volatile("s_waitcnt lgkmcnt(0)\n\ts_barrier" ::: "memory");
      if (flags != nullptr && (t & 31) == 31 && tid == 0)
        __hip_atomic_store(&flags[blockIdx.x * 8 + (t >> 5)], (t >> 5) + 1,
                           __ATOMIC_RELEASE, __HIP_MEMORY_SCOPE_AGENT);
    };

    for (int tp = 0; tp < S_LEN / 2; tp++) {
      const int t0 = 2 * tp, t1 = t0 + 1;
      sstep(t0, xprA);
      if (t0 + 2 < S_LEN) xprA = *(const f32x4*)(xpw + (size_t)(t0 + 2) * 2048);
      sstep(t1, xprB);
      if (t1 + 2 < S_LEN) xprB = *(const f32x4*)(xpw + (size_t)(t1 + 2) * 2048);
    }
  } else {
    // ========================= TAIL ROLE (R5-verified) =========================
    const int bt = blockIdx.x - 64;      // paired core block
    float w2g[5][8], Gs[5], Bs[5], wrow[5];
#pragma unroll
    for (int j = 0; j < 8; j++) {
      int c = l15 * 8 + j;               // plain row-major channels
      float gc = g1[c];
#pragma unroll
      for (int jj = 0; jj < 5; jj++) w2g[jj][j] = Wih2[jj * DIM + c] * gc;
    }
#pragma unroll
    for (int jj = 0; jj < 5; jj++) { Gs[jj] = 0.f; Bs[jj] = 0.f; }
    for (int c = 0; c < DIM; c++) {
      float gc = g1[c], bc = be1[c];
#pragma unroll
      for (int jj = 0; jj < 5; jj++) {
        float w = Wih2[jj * DIM + c];
        Gs[jj] += w * gc; Bs[jj] += w * bc;
      }
    }
    const float validf = (l15 < 5) ? 1.f : 0.f;
    float t2_l = 0.f, g2_l = 0.f, be2_l = 0.f;
    if (l15 < 5) {
      t2_l = bih2[l15] + bhh2[l15];
      g2_l = g2[l15]; be2_l = be2[l15];
#pragma unroll
      for (int jj = 0; jj < 5; jj++) wrow[jj] = Whh2[l15 * 5 + jj];
    } else {
#pragma unroll
      for (int jj = 0; jj < 5; jj++) wrow[jj] = 0.f;
    }
    float h2rep[5] = {0, 0, 0, 0, 0}, pool_l = 0.f;
    const int row_l = 2 * wave + (q & 1);          // this group's row
    const unsigned short* hb =
        hout + (size_t)(bt * 16 + row_l) * S_LEN * DIM;
    const int idx = (l15 < 5) ? l15 : 0;

    for (int c8 = 0; c8 < 8; c8++) {
      if (tid == 0) {                    // poisoned flag is negative: waits
        while (__hip_atomic_load(&flags[bt * 8 + c8], __ATOMIC_RELAXED,
                                 __HIP_MEMORY_SCOPE_AGENT) < c8 + 1)
          __builtin_amdgcn_s_sleep(2);
      }
      __syncthreads();
      __builtin_amdgcn_fence(__ATOMIC_ACQUIRE, "agent");   // reader-side inv
      // phase A: LN1+proj for this chunk (2 rows x 32 t over 4 groups)
      for (int tt = 0; tt < 16; tt++) {
        int toff = tt * 2 + (q >> 1);
        uint4 cur = *(const uint4*)(hb + (size_t)(c8 * 32 + toff) * DIM + l15 * 8);
        float hv[8];
        hv[0] = __uint_as_float(cur.x << 16); hv[1] = __uint_as_float(cur.x & 0xffff0000u);
        hv[2] = __uint_as_float(cur.y << 16); hv[3] = __uint_as_float(cur.y & 0xffff0000u);
        hv[4] = __uint_as_float(cur.z << 16); hv[5] = __uint_as_float(cur.z & 0xffff0000u);
        hv[6] = __uint_as_float(cur.w << 16); hv[7] = __uint_as_float(cur.w & 0xffff0000u);
        float s = 0.f, sq = 0.f, d[5] = {0, 0, 0, 0, 0};
#pragma unroll
        for (int j = 0; j < 8; j++) {
          float v = hv[j];
          s += v; sq += v * v;
#pragma unroll
          for (int jj = 0; jj < 5; jj++) d[jj] = fmaf(w2g[jj][j], v, d[jj]);
        }
        red_level7<0x124>(s, sq, d);
        red_level7<0x128>(s, sq, d);
        red_level7<0x39>(s, sq, d);
        red_level7<0x4E>(s, sq, d);
        float mean = s * (1.f / 128.f);
        float var  = sq * (1.f / 128.f) - mean * mean;
        float rstd = rsqrtf(var + EPSL);
        float p[5];
#pragma unroll
        for (int jj = 0; jj < 5; jj++)
          p[jj] = rstd * (d[jj] - mean * Gs[jj]) + Bs[jj];
        float psel = (l15 == 0) ? p[0] : (l15 == 1) ? p[1] :
                     (l15 == 2) ? p[2] : (l15 == 3) ? p[3] : p[4];
        if (l15 < 5) p_lds[wave][q & 1][toff][l15] = psel;
      }
      asm volatile("s_waitcnt lgkmcnt(0)" ::: "memory");   // wave-local
      // phase B: 32 serial RNN2/LN2/pool steps (group-local, 1 tanh/step)
      for (int s = 0; s < 32; s++) {
        float pv = p_lds[wave][q & 1][s][idx];
        float a = pv + t2_l;
#pragma unroll
        for (int jj = 0; jj < 5; jj++) a = fmaf(wrow[jj], h2rep[jj], a);
        float xn = tanh_fast(a);
        float s2 = dpp_sum16(xn * validf) * 0.2f;
        float dd = xn - s2;
        float v2 = dpp_sum16(dd * dd * validf) * 0.2f;
        float r2 = rsqrtf(v2 + EPSL);
        pool_l += dd * r2 * g2_l + be2_l;
        h2rep[0] = bcast16<0>(xn); h2rep[1] = bcast16<1>(xn);
        h2rep[2] = bcast16<2>(xn); h2rep[3] = bcast16<3>(xn);
        h2rep[4] = bcast16<4>(xn);
      }
    }
    float lg = pool_l * (1.f / 256.f);
    float mx = dpp_max16((l15 < 5) ? lg : -3.0e38f);
    float e  = (l15 < 5) ? __expf(lg - mx) : 0.f;
    float sm = dpp_sum16(e);
    if (q < 2 && l15 < 5)
      out[(size_t)(bt * 16 + row_l) * 5 + l15] = e / sm;
  }
}

// ================= rnn_main: R5-verified kernel (fallback, 177 us) ==========
__global__ __launch_bounds__(512, 2)
void rnn_main(const int* __restrict__ x, const float* __restrict__ emb,
              const float* __restrict__ Wih1, const float* __restrict__ bih1,
              const float* __restrict__ Whh1, const float* __restrict__ bhh1,
              const float* __restrict__ g1, const float* __restrict__ be1,
              const float* __restrict__ Wih2, const float* __restrict__ bih2,
              const float* __restrict__ Whh2, const float* __restrict__ bhh2,
              const float* __restrict__ g2, const float* __restrict__ be2,
              unsigned short* __restrict__ hout, int* flags,
              float* __restrict__ out)
{
  __shared__ __align__(16) unsigned short h_bf[2][16 * 128];   // 8 KB
  __shared__ __align__(16) unsigned short e_bf[2][16 * 128];   // 8 KB
  __shared__ int x_tile[16 * 256];                             // 16 KB
  __shared__ __align__(16) float p_lds[8][2][32][8];           // 16 KB (tail)

  const int tid  = threadIdx.x;
  const int wave = tid >> 6;
  const int lane = tid & 63;
  const int l15  = lane & 15;
  const int q    = lane >> 4;

  if (blockIdx.x < 64) {
    const int r0 = blockIdx.x * 16;
    for (int i = tid; i < 16 * 256; i += 512)
      x_tile[i] = x[(size_t)(r0 + (i >> 8)) * S_LEN + (i & 255)];
    for (int i = tid; i < 16 * 128; i += 512) h_bf[1][i] = 0;

    const int n1 = wave * 16 + l15;
    const float bias1v = bih1[n1] + bhh1[n1];
    bf16x8 wh[4], wih[4];
#pragma unroll
    for (int kt = 0; kt < 4; kt++) {
      int k0 = kt * 32 + q * 8;
      Frag8 fh, fa;
#pragma unroll
      for (int j = 0; j < 8; j++) {
        fh.us[j] = f2bf_bits(Whh1[n1 * DIM + k0 + j]);
        fa.us[j] = f2bf_bits(Wih1[n1 * DIM + k0 + j]);
      }
      wh[kt] = fh.v; wih[kt] = fa.v;
    }

    const int srow = wave * 2 + (lane >> 5);
    const int soct = (lane >> 1) & 15;
    const int ssub = lane & 1;
    const int sdst = srow * 128 + ((soct ^ srow) & 15) * 8 + ssub * 4;
    float4 pf[2];
    __syncthreads();

    {
      float4 ta, tb;
      { int xid = x_tile[srow * 256 + 0];
        ta = *(const float4*)(emb + (size_t)xid * DIM + soct * 8 + ssub * 4); }
      { int xid = x_tile[srow * 256 + 1];
        tb = *(const float4*)(emb + (size_t)xid * DIM + soct * 8 + ssub * 4); }
      { int xid = x_tile[srow * 256 + 2];
        pf[0] = *(const float4*)(emb + (size_t)xid * DIM + soct * 8 + ssub * 4); }
      { int xid = x_tile[srow * 256 + 3];
        pf[1] = *(const float4*)(emb + (size_t)xid * DIM + soct * 8 + ssub * 4); }
      int2 pa, pb;
      pa.x = (int)pack_rhu(ta.x, ta.y); pa.y = (int)pack_rhu(ta.z, ta.w);
      pb.x = (int)pack_rhu(tb.x, tb.y); pb.y = (int)pack_rhu(tb.z, tb.w);
      *(int2*)&e_bf[0][sdst] = pa;
      *(int2*)&e_bf[1][sdst] = pb;
    }
    __syncthreads();

    f32x4 xpacc = {bias1v, bias1v, bias1v, bias1v};
#pragma unroll
    for (int kt = 0; kt < 4; kt++) {
      int sw = (((kt * 4 + q) ^ l15) & 15) * 8;
      bf16x8 ae = *(const bf16x8*)&e_bf[0][l15 * 128 + sw];
      xpacc = __builtin_amdgcn_mfma_f32_16x16x32_bf16(ae, wih[kt], xpacc, 0, 0, 0);
    }
    asm volatile("s_waitcnt lgkmcnt(0)\n\ts_barrier" ::: "memory");

#pragma unroll 2
    for (int t = 0; t < S_LEN; t++) {
      f32x4 acc = xpacc;
      {
        const int rb = (t + 1) & 1;
#pragma unroll
        for (int kt = 0; kt < 4; kt++) {
          int sw = (((kt * 4 + q) ^ l15) & 15) * 8;
          bf16x8 ahf = *(const bf16x8*)&h_bf[rb][l15 * 128 + sw];
          acc = __builtin_amdgcn_mfma_f32_16x16x32_bf16(ahf, wh[kt], acc, 0, 0, 0);
        }
        const int wb = t & 1;
        const int oct = n1 >> 3;
#pragma unroll
        for (int r = 0; r < 4; r++) {
          int row = q * 4 + r;
          unsigned short us = (unsigned short)f2bf_rhu(tanh_fast(acc[r]));
          h_bf[wb][row * 128 + ((oct ^ row) & 15) * 8 + (n1 & 7)] = us;
          hout[((size_t)(r0 + row) * S_LEN + t) * DIM + n1] = us;
        }
      }

      if (t + 1 < S_LEN) {
        f32x4 a = {bias1v, bias1v, bias1v, bias1v};
#pragma unroll
        for (int kt = 0; kt < 4; kt++) {
          int sw = (((kt * 4 + q) ^ l15) & 15) * 8;
          bf16x8 ae = *(const bf16x8*)&e_bf[(t + 1) & 1][l15 * 128 + sw];
          a = __builtin_amdgcn_mfma_f32_16x16x32_bf16(ae, wih[kt], a, 0, 0, 0);
        }
        xpacc = a;
      }

      {
        if (t + 2 < S_LEN) {
          int2 pk;
          pk.x = (int)pack_rhu(pf[t & 1].x, pf[t & 1].y);
          pk.y = (int)pack_rhu(pf[t & 1].z, pf[t & 1].w);
          *(int2*)&e_bf[t & 1][sdst] = pk;
        }
        if (t + 4 < S_LEN) {
          int xid = x_tile[srow * 256 + t + 4];
          pf[t & 1] = *(const float4*)(emb + (size_t)xid * DIM + soct * 8 + ssub * 4);
        }
      }
      if (flags != nullptr && (t & 31) == 31)
        asm volatile("s_waitcnt vmcnt(0)" ::: "memory");
      asm volatile("s_waitcnt lgkmcnt(0)\n\ts_barrier" ::: "memory");
      if (flags != nullptr && (t & 31) == 31 && tid == 0)
        __hip_atomic_store(&flags[blockIdx.x * 8 + (t >> 5)], (t >> 5) + 1,
                           __ATOMIC_RELEASE, __HIP_MEMORY_SCOPE_AGENT);
    }
  } else {
    const int bt = blockIdx.x - 64;
    float w2g[5][8], Gs[5], Bs[5], wrow[5];
#pragma unroll
    for (int j = 0; j < 8; j++) {
      int c = l15 * 8 + j;
      float gc = g1[c];
#pragma unroll
      for (int jj = 0; jj < 5; jj++) w2g[jj][j] = Wih2[jj * DIM + c] * gc;
    }
#pragma unroll
    for (int jj = 0; jj < 5; jj++) { Gs[jj] = 0.f; Bs[jj] = 0.f; }
    for (int c = 0; c < DIM; c++) {
      float gc = g1[c], bc = be1[c];
#pragma unroll
      for (int jj = 0; jj < 5; jj++) {
        float w = Wih2[jj * DIM + c];
        Gs[jj] += w * gc; Bs[jj] += w * bc;
      }
    }
    const float validf = (l15 < 5) ? 1.f : 0.f;
    float t2_l = 0.f, g2_l = 0.f, be2_l = 0.f;
    if (l15 < 5) {
      t2_l = bih2[l15] + bhh2[l15];
      g2_l = g2[l15]; be2_l = be2[l15];
#pragma unroll
      for (int jj = 0; jj < 5; jj++) wrow[jj] = Whh2[l15 * 5 + jj];
    } else {
#pragma unroll
      for (int jj = 0; jj < 5; jj++) wrow[jj] = 0.f;
    }
    float h2rep[5] = {0, 0, 0, 0, 0}, pool_l = 0.f;
    const int row_l = 2 * wave + (q & 1);
    const unsigned short* hb =
        hout + (size_t)(bt * 16 + row_l) * S_LEN * DIM;
    const int idx = (l15 < 5) ? l15 : 0;

    for (int c8 = 0; c8 < 8; c8++) {
      if (tid == 0) {
        while (__hip_atomic_load(&flags[bt * 8 + c8], __ATOMIC_RELAXED,
                                 __HIP_MEMORY_SCOPE_AGENT) < c8 + 1)
          __builtin_amdgcn_s_sleep(2);
      }
      __syncthreads();
      __builtin_amdgcn_fence(__ATOMIC_ACQUIRE, "agent");
      for (int tt = 0; tt < 16; tt++) {
        int toff = tt * 2 + (q >> 1);
        uint4 cur = *(const uint4*)(hb + (size_t)(c8 * 32 + toff) * DIM + l15 * 8);
        float hv[8];
        hv[0] = __uint_as_float(cur.x << 16); hv[1] = __uint_as_float(cur.x & 0xffff0000u);
        hv[2] = __uint_as_float(cur.y << 16); hv[3] = __uint_as_float(cur.y & 0xffff0000u);
        hv[4] = __uint_as_float(cur.z << 16); hv[5] = __uint_as_float(cur.z & 0xffff0000u);
        hv[6] = __uint_as_float(cur.w << 16); hv[7] = __uint_as_float(cur.w & 0xffff0000u);
        float s = 0.f, sq = 0.f, d[5] = {0, 0, 0, 0, 0};
#pragma unroll
        for (int j = 0; j < 8; j++) {
          float v = hv[j];
          s += v; sq += v * v;
#pragma unroll
          for (int jj = 0; jj < 5; jj++) d[jj] = fmaf(w2g[jj][j], v, d[jj]);
        }
        red_level7<0x124>(s, sq, d);
        red_level7<0x128>(s, sq, d);
        red_level7<0x39>(s, sq, d);
        red_level7<0x4E>(s, sq, d);
        float mean = s * (1.f / 128.f);
        float var  = sq * (1.f / 128.f) - mean * mean;
        float rstd = rsqrtf(var + EPSL);
        float p[5];
#pragma unroll
        for (int jj = 0; jj < 5; jj++)
          p[jj] = rstd * (d[jj] - mean * Gs[jj]) + Bs[jj];
        float psel = (l15 == 0) ? p[0] : (l15 == 1) ? p[1] :
                     (l15 == 2) ? p[2] : (l15 == 3) ? p[3] : p[4];
        if (l15 < 5) p_lds[wave][q & 1][toff][l15] = psel;
      }
      asm volatile("s_waitcnt lgkmcnt(0)" ::: "memory");
      for (int s = 0; s < 32; s++) {
        float pv = p_lds[wave][q & 1][s][idx];
        float a = pv + t2_l;
#pragma unroll
        for (int jj = 0; jj < 5; jj++) a = fmaf(wrow[jj], h2rep[jj], a);
        float xn = tanh_fast(a);
        float s2 = dpp_sum16(xn * validf) * 0.2f;
        float dd = xn - s2;
        float v2 = dpp_sum16(dd * dd * validf) * 0.2f;
        float r2 = rsqrtf(v2 + EPSL);
        pool_l += dd * r2 * g2_l + be2_l;
        h2rep[0] = bcast16<0>(xn); h2rep[1] = bcast16<1>(xn);
        h2rep[2] = bcast16<2>(xn); h2rep[3] = bcast16<3>(xn);
        h2rep[4] = bcast16<4>(xn);
      }
    }
    float lg = pool_l * (1.f / 256.f);
    float mx = dpp_max16((l15 < 5) ? lg : -3.0e38f);
    float e  = (l15 < 5) ? __expf(lg - mx) : 0.f;
    float sm = dpp_sum16(e);
    if (q < 2 && l15 < 5)
      out[(size_t)(bt * 16 + row_l) * 5 + l15] = e / sm;
  }
}

// ============ rnn_tail_r11: fallback tail (R11, interleaved) ================
__global__ __launch_bounds__(256, 2)
void rnn_tail_r11(const unsigned short* __restrict__ hall,
                  const float* __restrict__ g1,  const float* __restrict__ be1,
                  const float* __restrict__ Wih2, const float* __restrict__ bih2,
                  const float* __restrict__ Whh2, const float* __restrict__ bhh2,
                  const float* __restrict__ g2,  const float* __restrict__ be2,
                  float* __restrict__ out)
{
  __shared__ float p_lds[4][4][8];
  const int tid  = threadIdx.x;
  const int wave = tid >> 6;
  const int lane = tid & 63;
  const int l15  = lane & 15;
  const int q    = lane >> 4;
  const int b    = blockIdx.x * 4 + wave;

  float w2g[5][8], Gs[5], Bs[5], wrow[5];
#pragma unroll
  for (int j = 0; j < 8; j++) {
    int c = l15 * 8 + j;
    float gc = g1[c];
#pragma unroll
    for (int jj = 0; jj < 5; jj++) w2g[jj][j] = Wih2[jj * DIM + c] * gc;
  }
#pragma unroll
  for (int jj = 0; jj < 5; jj++) { Gs[jj] = 0.f; Bs[jj] = 0.f; }
  for (int c = 0; c < DIM; c++) {
    float gc = g1[c], bc = be1[c];
#pragma unroll
    for (int jj = 0; jj < 5; jj++) {
      float w = Wih2[jj * DIM + c];
      Gs[jj] += w * gc; Bs[jj] += w * bc;
    }
  }
  const float validf = (l15 < 5) ? 1.f : 0.f;
  float t2_l = 0.f, g2_l = 0.f, be2_l = 0.f;
  if (l15 < 5) {
    t2_l = bih2[l15] + bhh2[l15];
    g2_l = g2[l15]; be2_l = be2[l15];
#pragma unroll
    for (int jj = 0; jj < 5; jj++) wrow[jj] = Whh2[l15 * 5 + jj];
  } else {
#pragma unroll
    for (int jj = 0; jj < 5; jj++) wrow[jj] = 0.f;
  }
  float h2rep[5];
#pragma unroll
  for (int jj = 0; jj < 5; jj++) h2rep[jj] = 0.f;
  float pool_l = 0.f;

  const unsigned short* hb = hall + (size_t)b * S_LEN * DIM;
  uint4 hpre = *(const uint4*)(hb + (size_t)q * DIM + l15 * 8);

  for (int t0 = 0; t0 < S_LEN; t0 += 4) {
    uint4 cur = hpre;
    if (t0 + 4 < S_LEN)
      hpre = *(const uint4*)(hb + (size_t)(t0 + 4 + q) * DIM + l15 * 8);
    float hv[8];
    hv[0] = __uint_as_float(cur.x << 16); hv[1] = __uint_as_float(cur.x & 0xffff0000u);
    hv[2] = __uint_as_float(cur.y << 16); hv[3] = __uint_as_float(cur.y & 0xffff0000u);
    hv[4] = __uint_as_float(cur.z << 16); hv[5] = __uint_as_float(cur.z & 0xffff0000u);
    hv[6] = __uint_as_float(cur.w << 16); hv[7] = __uint_as_float(cur.w & 0xffff0000u);
    float s = 0.f, sq = 0.f, d[5] = {0, 0, 0, 0, 0};
#pragma unroll
    for (int j = 0; j < 8; j++) {
      float v = hv[j];
      s += v; sq += v * v;
#pragma unroll
      for (int jj = 0; jj < 5; jj++) d[jj] = fmaf(w2g[jj][j], v, d[jj]);
    }
    red_level7<0x124>(s, sq, d);
    red_level7<0x128>(s, sq, d);
    red_level7<0x39>(s, sq, d);
    red_level7<0x4E>(s, sq, d);
    float mean = s * (1.f / 128.f);
    float var  = sq * (1.f / 128.f) - mean * mean;
    float rstd = rsqrtf(var + EPSL);
    float p[5];
#pragma unroll
    for (int jj = 0; jj < 5; jj++)
      p[jj] = rstd * (d[jj] - mean * Gs[jj]) + Bs[jj];
    float psel = (l15 == 0) ? p[0] : (l15 == 1) ? p[1] :
                 (l15 == 2) ? p[2] : (l15 == 3) ? p[3] : p[4];
    if (l15 < 5) p_lds[wave][q][l15] = psel;
    asm volatile("s_waitcnt lgkmcnt(0)" ::: "memory");
    const int idx = (l15 < 5) ? l15 : 0;
#pragma unroll
    for (int g = 0; g < 4; g++) {
      float pv = p_lds[wave][g][idx];
      float a = pv + t2_l;
#pragma unroll
      for (int jj = 0; jj < 5; jj++) a = fmaf(wrow[jj], h2rep[jj], a);
      float xn = tanh_fast(a);
      float s2 = dpp_sum16(xn * validf) * 0.2f;
      float dd = xn - s2;
      float v2 = dpp_sum16(dd * dd * validf) * 0.2f;
      float r2 = rsqrtf(v2 + EPSL);
      pool_l += dd * r2 * g2_l + be2_l;
      h2rep[0] = bcast16<0>(xn); h2rep[1] = bcast16<1>(xn);
      h2rep[2] = bcast16<2>(xn); h2rep[3] = bcast16<3>(xn);
      h2rep[4] = bcast16<4>(xn);
    }
  }

  float lg = pool_l * (1.f / 256.f);
  float mx = dpp_max16((l15 < 5) ? lg : -3.0e38f);
  float e  = (l15 < 5) ? __expf(lg - mx) : 0.f;
  float sm = dpp_sum16(e);
  if (q == 0 && l15 < 5) out[(size_t)b * 5 + l15] = e / sm;
}

extern "C" void kernel_launch(void* const* d_in, const int* in_sizes, int n_in,
                              void* d_out, int out_size, void* d_ws, size_t ws_size,
                              hipStream_t stream) {
  (void)in_sizes; (void)n_in; (void)out_size;
  const int*   x    = (const int*)  d_in[0];
  const float* emb  = (const float*)d_in[1];
  const float* Wih1 = (const float*)d_in[2];
  const float* bih1 = (const float*)d_in[3];
  const float* Whh1 = (const float*)d_in[4];
  const float* bhh1 = (const float*)d_in[5];
  const float* g1   = (const float*)d_in[6];
  const float* be1  = (const float*)d_in[7];
  const float* Wih2 = (const float*)d_in[8];
  const float* bih2 = (const float*)d_in[9];
  const float* Whh2 = (const float*)d_in[10];
  const float* bhh2 = (const float*)d_in[11];
  const float* g2   = (const float*)d_in[12];
  const float* be2  = (const float*)d_in[13];
  float* out = (float*)d_out;

  const size_t HBYTES  = (size_t)1024 * S_LEN * DIM * 2;        // 64 MiB bf16 h
  const size_t XPBYTES = (size_t)64 * S_LEN * 8 * 64 * 16;      // 128 MiB f32 xp
  unsigned short* hws = (unsigned short*)d_ws;

  if (ws_size >= HBYTES + 4096 + XPBYTES) {
    int*   flags = (int*)((char*)d_ws + HBYTES);
    float* xpg   = (float*)((char*)d_ws + HBYTES + 4096);
    rnn_xp<<<dim3(128), dim3(512), 0, stream>>>(
        x, emb, Wih1, bih1, Whh1, bhh1, g1, be1,
        Wih2, bih2, Whh2, bhh2, g2, be2, hws, flags, xpg, out);
  } else if (ws_size >= HBYTES + 4096) {
    // verified R5 path (177 us core)
    int* flags = (int*)((char*)d_ws + HBYTES);
    rnn_main<<<dim3(128), dim3(512), 0, stream>>>(
        x, emb, Wih1, bih1, Whh1, bhh1, g1, be1,
        Wih2, bih2, Whh2, bhh2, g2, be2, hws, flags, out);
  } else {
    // fallback: core-only mode (flags = nullptr) + R11 two-kernel tail
    rnn_main<<<dim3(64), dim3(512), 0, stream>>>(
        x, emb, Wih1, bih1, Whh1, bhh1, g1, be1,
        Wih2, bih2, Whh2, bhh2, g2, be2, hws, nullptr, out);
    rnn_tail_r11<<<dim3(256), dim3(256), 0, stream>>>(
        hws, g1, be1, Wih2, bih2, Whh2, bhh2, g2, be2, out);
  }
}